// Round 20
// baseline (82.999 us; speedup 1.0000x reference)
//
#include <hip/hip_runtime.h>
#include <hip/hip_bf16.h>
#include <utility>

#define LOG2E 1.4426950408889634f

#if __has_builtin(__builtin_amdgcn_exp2f)
#define EXP2F(x) __builtin_amdgcn_exp2f(x)
#else
#define EXP2F(x) exp2f(x)
#endif

#if __has_builtin(__builtin_amdgcn_rsqf)
#define RSQ(x) __builtin_amdgcn_rsqf(x)
#else
#define RSQ(x) (1.0f / sqrtf(x))
#endif

// readlane: lane may be a literal OR a runtime-uniform (SGPR) value.
#define RDLANE(x, l) __int_as_float(__builtin_amdgcn_readlane(__float_as_int(x), (l)))

// ---------------------------------------------------------------------------
// R20: FUSED single kernel. Two-kernel structure cost (~6-9us whole-GPU-idle
// precompute window + 2nd graph-node launch) is the only unattacked budget
// left (forward micro-opts R14-R19 all null within noise). Every block runs
// the R17 Cholesky redundantly -- all 4 waves execute identical code on
// identical inputs, so every LDS write is idempotent (same bit patterns) and
// the existing __syncthreads ordering makes it race-free. Then each block
// grid-strides the proven R14 forward over point chunks. 652 blocks at
// ~130 VGPR / 20KB LDS = 3 blocks/CU resident = ONE cohort: prologue paid
// once in wall time, in parallel across all CUs. ws is no longer used.
// ---------------------------------------------------------------------------
typedef float f16v __attribute__((ext_vector_type(16)));
struct Rows { f16v v0, v1, v2, v3; };

template<int J> __device__ __forceinline__ float getR(const Rows& r) {
    if constexpr (J < 16)      return r.v0[J];
    else if constexpr (J < 32) return r.v1[J - 16];
    else if constexpr (J < 48) return r.v2[J - 32];
    else                       return r.v3[J - 48];
}
template<int J> __device__ __forceinline__ void setR(Rows& r, float x) {
    if constexpr (J < 16)      r.v0[J] = x;
    else if constexpr (J < 32) r.v1[J - 16] = x;
    else if constexpr (J < 48) r.v2[J - 32] = x;
    else                       r.v3[J - 48] = x;
}

template<int LO, int W>
__device__ __forceinline__ float selR(const Rows& r, int k) {
    if constexpr (W == 1) {
        return getR<LO>(r);
    } else {
        float lo = selR<LO, W / 2>(r, k);
        float hi = selR<LO + W / 2, W / 2>(r, k);
        return (k & (W / 2)) ? hi : lo;   // uniform cond -> cndmask, CSE'd
    }
}

// Rank-1 update of one 4-column quad from a uniform float4 of lk values.
template<int Q>
__device__ __forceinline__ void upd_quad(Rows& r, float lk, const float4 lv) {
    setR<4 * Q + 0>(r, fmaf(-lk, lv.x, getR<4 * Q + 0>(r)));
    setR<4 * Q + 1>(r, fmaf(-lk, lv.y, getR<4 * Q + 1>(r)));
    setR<4 * Q + 2>(r, fmaf(-lk, lv.z, getR<4 * Q + 2>(r)));
    setR<4 * Q + 3>(r, fmaf(-lk, lv.w, getR<4 * Q + 3>(r)));
}
template<int QLO, int... Qs>
__device__ __forceinline__ void upd_quads(Rows& r, float lk, const float4* lkb4,
                                          std::integer_sequence<int, Qs...>) {
    (upd_quad<QLO + Qs>(r, lk, lkb4[QLO + Qs]), ...);
}

template<int... Js>
__device__ __forceinline__ void load_row(Rows& r, const float* Lrow,
                                         std::integer_sequence<int, Js...>) {
    (setR<Js>(r, Lrow[Js]), ...);
}

template<int KLO, int KHI, int ULO>
__device__ __forceinline__ void chol_phase(Rows& r, float* Lsh, float* lkbuf,
                                           int lane) {
    const float4* lkb4 = (const float4*)lkbuf;
#pragma clang loop unroll(disable)
    for (int k = KLO; k < KHI; ++k) {
        float rk  = selR<ULO, 64 - ULO>(r, k); // A[l][k] (valid l >= k)
        float dk  = RDLANE(rk, k);             // A[k][k], uniform
        float inv = RSQ(dk);                   // 1/L[k][k]
        float lk  = rk * inv;                  // L[l][k]
        float st  = (lane == k) ? inv : lk;    // diag slot stores reciprocal
        Lsh[lane * 65 + k] = st;               // sink column k (idempotent x4)
        lkbuf[lane] = lk;                      // publish lk (idempotent x4)
        __syncthreads();                       // order write -> read
        upd_quads<ULO / 4>(r, lk, lkb4,
                           std::make_integer_sequence<int, 16 - ULO / 4>{});
        __syncthreads();                       // reads done before next write
    }
}

__global__ __launch_bounds__(256)
void gp_fused(const float* __restrict__ X, const float* __restrict__ Z,
              const float* __restrict__ U, const float* __restrict__ sf_p,
              const float* __restrict__ ell_p, float* __restrict__ out,
              int n, int nChunks) {
    __shared__ float Lsh[64 * 65];
    __shared__ float4 zbuf[64];
    __shared__ __align__(16) float lkbuf[64];
    __shared__ float4 P[128];

    const int lane = threadIdx.x & 63;     // all 4 waves run redundantly
    const float sf  = sf_p[0];
    const float ell = ell_p[0];
    const float inv_ell = 1.0f / ell;
    const float sf2 = sf * sf;

    // ---- Prologue: redundant per-block Cholesky (R17 code, 4x idempotent) --
    {
        const float z0 = Z[lane * 3 + 0] * inv_ell;
        const float z1 = Z[lane * 3 + 1] * inv_ell;
        const float z2 = Z[lane * 3 + 2] * inv_ell;

        zbuf[lane] = make_float4(z0, z1, z2, 0.0f);
        __syncthreads();

#pragma unroll 4
        for (int j = 0; j < 64; ++j) {
            float4 zj = zbuf[j];
            float dx = z0 - zj.x;
            float dy = z1 - zj.y;
            float dz = z2 - zj.z;
            float sq = dx * dx + dy * dy + dz * dz;
            Lsh[lane * 65 + j] = sf2 * EXP2F(-0.5f * LOG2E * sq);
        }
        __syncthreads();

        Rows r;
        load_row(r, &Lsh[lane * 65], std::make_integer_sequence<int, 64>{});

        chol_phase< 0, 32,  0>(r, Lsh, lkbuf, lane);
        chol_phase<32, 48, 32>(r, Lsh, lkbuf, lane);
        chol_phase<48, 64, 48>(r, Lsh, lkbuf, lane);
        __syncthreads();

        // Solve L^T W = U (column sweep, descending i), redundant per wave.
        float s0 = U[lane * 2 + 0];
        float s1 = U[lane * 2 + 1];
        float w0v = 0.0f, w1v = 0.0f;
#pragma unroll 8
        for (int i = 63; i >= 0; --i) {
            float a   = Lsh[i * 65 + lane];  // L[i][lane]; lane i: 1/L[i][i]
            float rdi = RDLANE(a, i);        // 1/L[i][i]
            float w0  = RDLANE(s0, i) * rdi; // W[i][0]
            float w1  = RDLANE(s1, i) * rdi; // W[i][1]
            bool  me  = (lane == i);
            w0v = me ? w0 : w0v;
            w1v = me ? w1 : w1v;
            s0 = fmaf(-a, w0, s0);
            s1 = fmaf(-a, w1, s1);
        }

        const float dm = -0.5f * LOG2E * (z0 * z0 + z1 * z1 + z2 * z2);
        P[2 * lane + 0] = make_float4(z0, z1, z2, dm);        // idempotent x4
        P[2 * lane + 1] = make_float4(sf2 * w0v, sf2 * w1v, 0.0f, 0.0f);
        __syncthreads();
    }

    // ---- Forward: R14 body, grid-strided over 512-point chunks -------------
    for (int chunk = blockIdx.x; chunk < nChunks; chunk += gridDim.x) {
        const int t  = chunk * 256 + (int)threadIdx.x;
        const int i0 = 2 * t;

        float p00, p01, p02, p10, p11, p12;
        if (i0 + 1 < n) {
            const float2* X2 = (const float2*)X;
            float2 xa = X2[3 * t + 0];
            float2 xb = X2[3 * t + 1];
            float2 xc = X2[3 * t + 2];
            p00 = xa.x; p01 = xa.y; p02 = xb.x;
            p10 = xb.y; p11 = xc.x; p12 = xc.y;
        } else if (i0 < n) {
            p00 = X[3 * i0 + 0]; p01 = X[3 * i0 + 1]; p02 = X[3 * i0 + 2];
            p10 = p00; p11 = p01; p12 = p02;
        } else {
            p00 = p01 = p02 = p10 = p11 = p12 = 0.0f;
        }

        float xt0[2], xt1[2], xt2[2], c[2];
        {
            float xs0 = p00 * inv_ell, xs1 = p01 * inv_ell, xs2 = p02 * inv_ell;
            c[0]  = -0.5f * LOG2E * (xs0 * xs0 + xs1 * xs1 + xs2 * xs2);
            xt0[0] = xs0 * LOG2E; xt1[0] = xs1 * LOG2E; xt2[0] = xs2 * LOG2E;
            xs0 = p10 * inv_ell; xs1 = p11 * inv_ell; xs2 = p12 * inv_ell;
            c[1]  = -0.5f * LOG2E * (xs0 * xs0 + xs1 * xs1 + xs2 * xs2);
            xt0[1] = xs0 * LOG2E; xt1[1] = xs1 * LOG2E; xt2[1] = xs2 * LOG2E;
        }

        float acc0[2] = {0.f, 0.f};
        float acc1[2] = {0.f, 0.f};

#pragma unroll 4
        for (int m = 0; m < 64; ++m) {
            const float4 a = P[2 * m + 0];
            const float4 b = P[2 * m + 1];
#pragma unroll
            for (int p = 0; p < 2; ++p) {
                float arg = fmaf(xt0[p], a.x,
                            fmaf(xt1[p], a.y,
                            fmaf(xt2[p], a.z, c[p] + a.w)));
                float e = EXP2F(arg);
                acc0[p] = fmaf(e, b.x, acc0[p]);
                acc1[p] = fmaf(e, b.y, acc1[p]);
            }
        }

        if (i0 + 1 < n) {
            ((float4*)out)[t] = make_float4(acc0[0], acc1[0], acc0[1], acc1[1]);
        } else if (i0 < n) {
            ((float2*)out)[i0] = make_float2(acc0[0], acc1[0]);
        }
    }
}

extern "C" void kernel_launch(void* const* d_in, const int* in_sizes, int n_in,
                              void* d_out, int out_size, void* d_ws, size_t ws_size,
                              hipStream_t stream) {
    // setup_inputs order: t, X, Z, U, sf, ell
    const float* X    = (const float*)d_in[1];
    const float* Z    = (const float*)d_in[2];
    const float* U    = (const float*)d_in[3];
    const float* sf   = (const float*)d_in[4];
    const float* ell  = (const float*)d_in[5];
    float* out = (float*)d_out;
    const int N = in_sizes[1] / 3;

    const int nChunks = (N + 511) / 512;         // 512 points per chunk
    int blocks = (nChunks + 2) / 3;              // ~3 chunks per block
    if (blocks < 1) blocks = 1;                  // => 652 blocks at N=1e6:
                                                 // 2.55/CU, one cohort
    gp_fused<<<blocks, 256, 0, stream>>>(X, Z, U, sf, ell, out, N, nChunks);
}

// Round 21
// 38.690 us; speedup vs baseline: 2.1452x; 2.1452x over previous
//
#include <hip/hip_runtime.h>
#include <hip/hip_bf16.h>
#include <utility>

#define LOG2E 1.4426950408889634f

#if __has_builtin(__builtin_amdgcn_exp2f)
#define EXP2F(x) __builtin_amdgcn_exp2f(x)
#else
#define EXP2F(x) exp2f(x)
#endif

#if __has_builtin(__builtin_amdgcn_rsqf)
#define RSQ(x) __builtin_amdgcn_rsqf(x)
#else
#define RSQ(x) (1.0f / sqrtf(x))
#endif

// readlane: lane may be a literal OR a runtime-uniform (SGPR) value.
#define RDLANE(x, l) __int_as_float(__builtin_amdgcn_readlane(__float_as_int(x), (l)))

// ---------------------------------------------------------------------------
// Kernel 1, R21: R17 minus the 128 per-step s_barriers. The workgroup is ONE
// wave: DS ops from a single wave issue in order through the LDS pipe, and
// the compiler must insert s_waitcnt lgkmcnt before the dependent quad reads
// (lkbuf write may-alias the reads). So the write->read and read->next-write
// orderings hold without s_barrier. (R20's fusion regressed 2.1x: VGPR 44 ->
// Rows spilled to scratch + 162K bank conflicts from 4 redundant waves;
// reverted to the proven two-kernel R17 structure.)
// ---------------------------------------------------------------------------
typedef float f16v __attribute__((ext_vector_type(16)));
struct Rows { f16v v0, v1, v2, v3; };

template<int J> __device__ __forceinline__ float getR(const Rows& r) {
    if constexpr (J < 16)      return r.v0[J];
    else if constexpr (J < 32) return r.v1[J - 16];
    else if constexpr (J < 48) return r.v2[J - 32];
    else                       return r.v3[J - 48];
}
template<int J> __device__ __forceinline__ void setR(Rows& r, float x) {
    if constexpr (J < 16)      r.v0[J] = x;
    else if constexpr (J < 32) r.v1[J - 16] = x;
    else if constexpr (J < 48) r.v2[J - 32] = x;
    else                       r.v3[J - 48] = x;
}

template<int LO, int W>
__device__ __forceinline__ float selR(const Rows& r, int k) {
    if constexpr (W == 1) {
        return getR<LO>(r);
    } else {
        float lo = selR<LO, W / 2>(r, k);
        float hi = selR<LO + W / 2, W / 2>(r, k);
        return (k & (W / 2)) ? hi : lo;   // uniform cond -> cndmask, CSE'd
    }
}

// Rank-1 update of one 4-column quad from a uniform float4 of lk values.
template<int Q>
__device__ __forceinline__ void upd_quad(Rows& r, float lk, const float4 lv) {
    setR<4 * Q + 0>(r, fmaf(-lk, lv.x, getR<4 * Q + 0>(r)));
    setR<4 * Q + 1>(r, fmaf(-lk, lv.y, getR<4 * Q + 1>(r)));
    setR<4 * Q + 2>(r, fmaf(-lk, lv.z, getR<4 * Q + 2>(r)));
    setR<4 * Q + 3>(r, fmaf(-lk, lv.w, getR<4 * Q + 3>(r)));
}
template<int QLO, int... Qs>
__device__ __forceinline__ void upd_quads(Rows& r, float lk, const float4* lkb4,
                                          std::integer_sequence<int, Qs...>) {
    (upd_quad<QLO + Qs>(r, lk, lkb4[QLO + Qs]), ...);
}

template<int... Js>
__device__ __forceinline__ void load_row(Rows& r, const float* Lrow,
                                         std::integer_sequence<int, Js...>) {
    (setR<Js>(r, Lrow[Js]), ...);
}

template<int KLO, int KHI, int ULO>
__device__ __forceinline__ void chol_phase(Rows& r, float* Lsh, float* lkbuf,
                                           int lane) {
    const float4* lkb4 = (const float4*)lkbuf;
#pragma clang loop unroll(disable)
    for (int k = KLO; k < KHI; ++k) {
        float rk  = selR<ULO, 64 - ULO>(r, k); // A[l][k] (valid l >= k)
        float dk  = RDLANE(rk, k);             // A[k][k], uniform
        float inv = RSQ(dk);                   // 1/L[k][k]
        float lk  = rk * inv;                  // L[l][k]
        float st  = (lane == k) ? inv : lk;    // diag slot stores reciprocal
        Lsh[lane * 65 + k] = st;               // sink column k (conflict-free)
        lkbuf[lane] = lk;                      // publish lk for the update
        // No s_barrier: single-wave DS is in-order and the compiler inserts
        // lgkmcnt before the dependent (may-aliasing) quad reads.
        upd_quads<ULO / 4>(r, lk, lkb4,
                           std::make_integer_sequence<int, 16 - ULO / 4>{});
    }
}

__global__ __launch_bounds__(64, 1)
void gp_precompute(const float* __restrict__ Z, const float* __restrict__ U,
                   const float* __restrict__ sf_p, const float* __restrict__ ell_p,
                   float* __restrict__ ws) {
    __shared__ float Lsh[64 * 65];
    __shared__ float4 zbuf[64];
    __shared__ __align__(16) float lkbuf[64];
    const int lane = threadIdx.x;          // 64 threads = 1 wave
    const float sf  = sf_p[0];
    const float ell = ell_p[0];
    const float inv_ell = 1.0f / ell;
    const float sf2 = sf * sf;

    const float z0 = Z[lane * 3 + 0] * inv_ell;
    const float z1 = Z[lane * 3 + 1] * inv_ell;
    const float z2 = Z[lane * 3 + 2] * inv_ell;

    zbuf[lane] = make_float4(z0, z1, z2, 0.0f);
    __syncthreads();

    // Kzz row init: one uniform b128 per j.
#pragma unroll 4
    for (int j = 0; j < 64; ++j) {
        float4 zj = zbuf[j];
        float dx = z0 - zj.x;
        float dy = z1 - zj.y;
        float dz = z2 - zj.z;
        float sq = dx * dx + dy * dy + dz * dz;
        Lsh[lane * 65 + j] = sf2 * EXP2F(-0.5f * LOG2E * sq);
    }
    __syncthreads();

    Rows r;
    load_row(r, &Lsh[lane * 65], std::make_integer_sequence<int, 64>{});

    chol_phase< 0, 32,  0>(r, Lsh, lkbuf, lane);
    chol_phase<32, 48, 32>(r, Lsh, lkbuf, lane);
    chol_phase<48, 64, 48>(r, Lsh, lkbuf, lane);
    __syncthreads();

    // Solve L^T W = U (column sweep, descending i).
    float s0 = U[lane * 2 + 0];
    float s1 = U[lane * 2 + 1];
    float w0v = 0.0f, w1v = 0.0f;
#pragma unroll 8
    for (int i = 63; i >= 0; --i) {
        float a   = Lsh[i * 65 + lane];    // L[i][lane]; lane i: 1/L[i][i]
        float rdi = RDLANE(a, i);          // 1/L[i][i]
        float w0  = RDLANE(s0, i) * rdi;   // W[i][0]
        float w1  = RDLANE(s1, i) * rdi;   // W[i][1]
        bool  me  = (lane == i);
        w0v = me ? w0 : w0v;
        w1v = me ? w1 : w1v;
        s0 = fmaf(-a, w0, s0);             // lanes >= i polluted after use
        s1 = fmaf(-a, w1, s1);
    }

    const float dm = -0.5f * LOG2E * (z0 * z0 + z1 * z1 + z2 * z2);
    float4* ws4 = (float4*)ws;
    ws4[lane * 2 + 0] = make_float4(z0, z1, z2, dm);
    ws4[lane * 2 + 1] = make_float4(sf2 * w0v, sf2 * w1v, 0.0f, 0.0f);
}

// ---------------------------------------------------------------------------
// Kernel 2 (byte-identical to R14/R17, the best measured forward).
// ---------------------------------------------------------------------------
__global__ __launch_bounds__(256) void gp_forward(const float* __restrict__ X,
                                                  const float* __restrict__ ws,
                                                  const float* __restrict__ ell_p,
                                                  float* __restrict__ out, int n) {
    __shared__ float4 P[128];   // 64 structs of {zs0,zs1,zs2,dm | w0,w1,0,0}
    for (int i = threadIdx.x; i < 128; i += 256)
        P[i] = ((const float4*)ws)[i];
    const float inv_ell = 1.0f / ell_p[0];
    __syncthreads();

    const int t  = blockIdx.x * 256 + threadIdx.x;  // global thread id
    const int i0 = 2 * t;                            // first of 2 points

    // Load 6 contiguous floats (2 points x 3 dims) as 3 aligned float2.
    float p00, p01, p02, p10, p11, p12;
    if (i0 + 1 < n) {
        const float2* X2 = (const float2*)X;
        float2 xa = X2[3 * t + 0];
        float2 xb = X2[3 * t + 1];
        float2 xc = X2[3 * t + 2];
        p00 = xa.x; p01 = xa.y; p02 = xb.x;
        p10 = xb.y; p11 = xc.x; p12 = xc.y;
    } else if (i0 < n) {
        p00 = X[3 * i0 + 0]; p01 = X[3 * i0 + 1]; p02 = X[3 * i0 + 2];
        p10 = p00; p11 = p01; p12 = p02;
    } else {
        p00 = p01 = p02 = p10 = p11 = p12 = 0.0f;
    }

    float xt0[2], xt1[2], xt2[2], c[2];
    {
        float xs0 = p00 * inv_ell, xs1 = p01 * inv_ell, xs2 = p02 * inv_ell;
        c[0]  = -0.5f * LOG2E * (xs0 * xs0 + xs1 * xs1 + xs2 * xs2);
        xt0[0] = xs0 * LOG2E; xt1[0] = xs1 * LOG2E; xt2[0] = xs2 * LOG2E;
        xs0 = p10 * inv_ell; xs1 = p11 * inv_ell; xs2 = p12 * inv_ell;
        c[1]  = -0.5f * LOG2E * (xs0 * xs0 + xs1 * xs1 + xs2 * xs2);
        xt0[1] = xs0 * LOG2E; xt1[1] = xs1 * LOG2E; xt2[1] = xs2 * LOG2E;
    }

    float acc0[2] = {0.f, 0.f};
    float acc1[2] = {0.f, 0.f};

#pragma unroll 4
    for (int m = 0; m < 64; ++m) {          // register-lean: 4-iter window
        const float4 a = P[2 * m + 0];
        const float4 b = P[2 * m + 1];
#pragma unroll
        for (int p = 0; p < 2; ++p) {
            float arg = fmaf(xt0[p], a.x,
                        fmaf(xt1[p], a.y,
                        fmaf(xt2[p], a.z, c[p] + a.w)));
            float e = EXP2F(arg);
            acc0[p] = fmaf(e, b.x, acc0[p]);
            acc1[p] = fmaf(e, b.y, acc1[p]);
        }
    }

    if (i0 + 1 < n) {
        ((float4*)out)[t] = make_float4(acc0[0], acc1[0], acc0[1], acc1[1]);
    } else if (i0 < n) {
        ((float2*)out)[i0] = make_float2(acc0[0], acc1[0]);
    }
}

extern "C" void kernel_launch(void* const* d_in, const int* in_sizes, int n_in,
                              void* d_out, int out_size, void* d_ws, size_t ws_size,
                              hipStream_t stream) {
    // setup_inputs order: t, X, Z, U, sf, ell
    const float* X    = (const float*)d_in[1];
    const float* Z    = (const float*)d_in[2];
    const float* U    = (const float*)d_in[3];
    const float* sf   = (const float*)d_in[4];
    const float* ell  = (const float*)d_in[5];
    float* out = (float*)d_out;
    float* ws  = (float*)d_ws;
    const int N = in_sizes[1] / 3;

    gp_precompute<<<1, 64, 0, stream>>>(Z, U, sf, ell, ws);

    const int PTS_PER_BLOCK = 256 * 2;      // 2 points per thread
    const int blocks = (N + PTS_PER_BLOCK - 1) / PTS_PER_BLOCK;
    gp_forward<<<blocks, 256, 0, stream>>>(X, ws, ell, out, N);
}

// Round 23
// 38.549 us; speedup vs baseline: 2.1531x; 1.0037x over previous
//
#include <hip/hip_runtime.h>
#include <hip/hip_bf16.h>
#include <utility>

#define LOG2E 1.4426950408889634f

#if __has_builtin(__builtin_amdgcn_exp2f)
#define EXP2F(x) __builtin_amdgcn_exp2f(x)
#else
#define EXP2F(x) exp2f(x)
#endif

#if __has_builtin(__builtin_amdgcn_rsqf)
#define RSQ(x) __builtin_amdgcn_rsqf(x)
#else
#define RSQ(x) (1.0f / sqrtf(x))
#endif

// readlane: lane may be a literal OR a runtime-uniform (SGPR) value.
#define RDLANE(x, l) __int_as_float(__builtin_amdgcn_readlane(__float_as_int(x), (l)))

// ---------------------------------------------------------------------------
// Kernel 1 (byte-identical to R21): barrier-free LDS-quad-broadcast Cholesky.
// ---------------------------------------------------------------------------
typedef float f16v __attribute__((ext_vector_type(16)));
struct Rows { f16v v0, v1, v2, v3; };

template<int J> __device__ __forceinline__ float getR(const Rows& r) {
    if constexpr (J < 16)      return r.v0[J];
    else if constexpr (J < 32) return r.v1[J - 16];
    else if constexpr (J < 48) return r.v2[J - 32];
    else                       return r.v3[J - 48];
}
template<int J> __device__ __forceinline__ void setR(Rows& r, float x) {
    if constexpr (J < 16)      r.v0[J] = x;
    else if constexpr (J < 32) r.v1[J - 16] = x;
    else if constexpr (J < 48) r.v2[J - 32] = x;
    else                       r.v3[J - 48] = x;
}

template<int LO, int W>
__device__ __forceinline__ float selR(const Rows& r, int k) {
    if constexpr (W == 1) {
        return getR<LO>(r);
    } else {
        float lo = selR<LO, W / 2>(r, k);
        float hi = selR<LO + W / 2, W / 2>(r, k);
        return (k & (W / 2)) ? hi : lo;   // uniform cond -> cndmask, CSE'd
    }
}

// Rank-1 update of one 4-column quad from a uniform float4 of lk values.
template<int Q>
__device__ __forceinline__ void upd_quad(Rows& r, float lk, const float4 lv) {
    setR<4 * Q + 0>(r, fmaf(-lk, lv.x, getR<4 * Q + 0>(r)));
    setR<4 * Q + 1>(r, fmaf(-lk, lv.y, getR<4 * Q + 1>(r)));
    setR<4 * Q + 2>(r, fmaf(-lk, lv.z, getR<4 * Q + 2>(r)));
    setR<4 * Q + 3>(r, fmaf(-lk, lv.w, getR<4 * Q + 3>(r)));
}
template<int QLO, int... Qs>
__device__ __forceinline__ void upd_quads(Rows& r, float lk, const float4* lkb4,
                                          std::integer_sequence<int, Qs...>) {
    (upd_quad<QLO + Qs>(r, lk, lkb4[QLO + Qs]), ...);
}

template<int... Js>
__device__ __forceinline__ void load_row(Rows& r, const float* Lrow,
                                         std::integer_sequence<int, Js...>) {
    (setR<Js>(r, Lrow[Js]), ...);
}

template<int KLO, int KHI, int ULO>
__device__ __forceinline__ void chol_phase(Rows& r, float* Lsh, float* lkbuf,
                                           int lane) {
    const float4* lkb4 = (const float4*)lkbuf;
#pragma clang loop unroll(disable)
    for (int k = KLO; k < KHI; ++k) {
        float rk  = selR<ULO, 64 - ULO>(r, k); // A[l][k] (valid l >= k)
        float dk  = RDLANE(rk, k);             // A[k][k], uniform
        float inv = RSQ(dk);                   // 1/L[k][k]
        float lk  = rk * inv;                  // L[l][k]
        float st  = (lane == k) ? inv : lk;    // diag slot stores reciprocal
        Lsh[lane * 65 + k] = st;               // sink column k (conflict-free)
        lkbuf[lane] = lk;                      // publish lk for the update
        // No s_barrier: single-wave DS is in-order; compiler inserts lgkmcnt.
        upd_quads<ULO / 4>(r, lk, lkb4,
                           std::make_integer_sequence<int, 16 - ULO / 4>{});
    }
}

__global__ __launch_bounds__(64, 1)
void gp_precompute(const float* __restrict__ Z, const float* __restrict__ U,
                   const float* __restrict__ sf_p, const float* __restrict__ ell_p,
                   float* __restrict__ ws) {
    __shared__ float Lsh[64 * 65];
    __shared__ float4 zbuf[64];
    __shared__ __align__(16) float lkbuf[64];
    const int lane = threadIdx.x;          // 64 threads = 1 wave
    const float sf  = sf_p[0];
    const float ell = ell_p[0];
    const float inv_ell = 1.0f / ell;
    const float sf2 = sf * sf;

    const float z0 = Z[lane * 3 + 0] * inv_ell;
    const float z1 = Z[lane * 3 + 1] * inv_ell;
    const float z2 = Z[lane * 3 + 2] * inv_ell;

    zbuf[lane] = make_float4(z0, z1, z2, 0.0f);
    __syncthreads();

    // Kzz row init: one uniform b128 per j.
#pragma unroll 4
    for (int j = 0; j < 64; ++j) {
        float4 zj = zbuf[j];
        float dx = z0 - zj.x;
        float dy = z1 - zj.y;
        float dz = z2 - zj.z;
        float sq = dx * dx + dy * dy + dz * dz;
        Lsh[lane * 65 + j] = sf2 * EXP2F(-0.5f * LOG2E * sq);
    }
    __syncthreads();

    Rows r;
    load_row(r, &Lsh[lane * 65], std::make_integer_sequence<int, 64>{});

    chol_phase< 0, 32,  0>(r, Lsh, lkbuf, lane);
    chol_phase<32, 48, 32>(r, Lsh, lkbuf, lane);
    chol_phase<48, 64, 48>(r, Lsh, lkbuf, lane);
    __syncthreads();

    // Solve L^T W = U (column sweep, descending i).
    float s0 = U[lane * 2 + 0];
    float s1 = U[lane * 2 + 1];
    float w0v = 0.0f, w1v = 0.0f;
#pragma unroll 8
    for (int i = 63; i >= 0; --i) {
        float a   = Lsh[i * 65 + lane];    // L[i][lane]; lane i: 1/L[i][i]
        float rdi = RDLANE(a, i);          // 1/L[i][i]
        float w0  = RDLANE(s0, i) * rdi;   // W[i][0]
        float w1  = RDLANE(s1, i) * rdi;   // W[i][1]
        bool  me  = (lane == i);
        w0v = me ? w0 : w0v;
        w1v = me ? w1 : w1v;
        s0 = fmaf(-a, w0, s0);             // lanes >= i polluted after use
        s1 = fmaf(-a, w1, s1);
    }

    const float dm = -0.5f * LOG2E * (z0 * z0 + z1 * z1 + z2 * z2);
    float4* ws4 = (float4*)ws;
    ws4[lane * 2 + 0] = make_float4(z0, z1, z2, dm);
    ws4[lane * 2 + 1] = make_float4(sf2 * w0v, sf2 * w1v, 0.0f, 0.0f);
}

// ---------------------------------------------------------------------------
// Kernel 2, R22 (resubmit): R14 body, GRID-STRIDED at ~2 chunks/block
// (489 blocks). Per-block fixed costs (P-stage + barrier + first-X vmcnt
// stall) paid once, amortized over 2x m-loop work; chunk k+1's independent
// X loads overlap chunk k's m-loop tail; block ramp/drain halves.
// ---------------------------------------------------------------------------
__global__ __launch_bounds__(256) void gp_forward(const float* __restrict__ X,
                                                  const float* __restrict__ ws,
                                                  const float* __restrict__ ell_p,
                                                  float* __restrict__ out,
                                                  int n, int nChunks) {
    __shared__ float4 P[128];   // 64 structs of {zs0,zs1,zs2,dm | w0,w1,0,0}
    for (int i = threadIdx.x; i < 128; i += 256)
        P[i] = ((const float4*)ws)[i];
    const float inv_ell = 1.0f / ell_p[0];
    __syncthreads();

    for (int chunk = blockIdx.x; chunk < nChunks; chunk += gridDim.x) {
        const int t  = chunk * 256 + (int)threadIdx.x;
        const int i0 = 2 * t;

        float p00, p01, p02, p10, p11, p12;
        if (i0 + 1 < n) {
            const float2* X2 = (const float2*)X;
            float2 xa = X2[3 * t + 0];
            float2 xb = X2[3 * t + 1];
            float2 xc = X2[3 * t + 2];
            p00 = xa.x; p01 = xa.y; p02 = xb.x;
            p10 = xb.y; p11 = xc.x; p12 = xc.y;
        } else if (i0 < n) {
            p00 = X[3 * i0 + 0]; p01 = X[3 * i0 + 1]; p02 = X[3 * i0 + 2];
            p10 = p00; p11 = p01; p12 = p02;
        } else {
            p00 = p01 = p02 = p10 = p11 = p12 = 0.0f;
        }

        float xt0[2], xt1[2], xt2[2], c[2];
        {
            float xs0 = p00 * inv_ell, xs1 = p01 * inv_ell, xs2 = p02 * inv_ell;
            c[0]  = -0.5f * LOG2E * (xs0 * xs0 + xs1 * xs1 + xs2 * xs2);
            xt0[0] = xs0 * LOG2E; xt1[0] = xs1 * LOG2E; xt2[0] = xs2 * LOG2E;
            xs0 = p10 * inv_ell; xs1 = p11 * inv_ell; xs2 = p12 * inv_ell;
            c[1]  = -0.5f * LOG2E * (xs0 * xs0 + xs1 * xs1 + xs2 * xs2);
            xt0[1] = xs0 * LOG2E; xt1[1] = xs1 * LOG2E; xt2[1] = xs2 * LOG2E;
        }

        float acc0[2] = {0.f, 0.f};
        float acc1[2] = {0.f, 0.f};

#pragma unroll 4
        for (int m = 0; m < 64; ++m) {
            const float4 a = P[2 * m + 0];
            const float4 b = P[2 * m + 1];
#pragma unroll
            for (int p = 0; p < 2; ++p) {
                float arg = fmaf(xt0[p], a.x,
                            fmaf(xt1[p], a.y,
                            fmaf(xt2[p], a.z, c[p] + a.w)));
                float e = EXP2F(arg);
                acc0[p] = fmaf(e, b.x, acc0[p]);
                acc1[p] = fmaf(e, b.y, acc1[p]);
            }
        }

        if (i0 + 1 < n) {
            ((float4*)out)[t] = make_float4(acc0[0], acc1[0], acc0[1], acc1[1]);
        } else if (i0 < n) {
            ((float2*)out)[i0] = make_float2(acc0[0], acc1[0]);
        }
    }
}

extern "C" void kernel_launch(void* const* d_in, const int* in_sizes, int n_in,
                              void* d_out, int out_size, void* d_ws, size_t ws_size,
                              hipStream_t stream) {
    // setup_inputs order: t, X, Z, U, sf, ell
    const float* X    = (const float*)d_in[1];
    const float* Z    = (const float*)d_in[2];
    const float* U    = (const float*)d_in[3];
    const float* sf   = (const float*)d_in[4];
    const float* ell  = (const float*)d_in[5];
    float* out = (float*)d_out;
    float* ws  = (float*)d_ws;
    const int N = in_sizes[1] / 3;

    gp_precompute<<<1, 64, 0, stream>>>(Z, U, sf, ell, ws);

    const int nChunks = (N + 511) / 512;    // 512 points (2/thread) per chunk
    int blocks = (nChunks + 1) / 2;         // ~2 chunks per block: 489 blocks
    if (blocks < 1) blocks = 1;
    gp_forward<<<blocks, 256, 0, stream>>>(X, ws, ell, out, N, nChunks);
}